// Round 1
// baseline (416.834 us; speedup 1.0000x reference)
//
#include <hip/hip_runtime.h>

#define B_  16
#define S_  1024
#define D_  384
#define QK_ 64

typedef __attribute__((ext_vector_type(8))) short bf16x8;
typedef __attribute__((ext_vector_type(4))) short bf16x4;
typedef __attribute__((ext_vector_type(4))) float f32x4;

__device__ __forceinline__ short f2bf(float f) {
  union { float f; unsigned u; } v; v.f = f;
  unsigned r = v.u + 0x7FFFu + ((v.u >> 16) & 1u);   // round-to-nearest-even
  return (short)(r >> 16);
}

__device__ __forceinline__ bf16x4 cvt4(const float4 v) {
  bf16x4 r;
  r[0] = f2bf(v.x); r[1] = f2bf(v.y); r[2] = f2bf(v.z); r[3] = f2bf(v.w);
  return r;
}

// ---------------------------------------------------------------------------
// K1: per-position projection.  For position n:  [16 x 384] x [384 x 128]^T
// -> Q[16][64] (scaled, +bias) and K[16][64], stored bf16 into workspace.
// One block per position, 4 waves. MFMA 16x16x32 bf16: M=batch(16),
// N=j tile (8 tiles of 16 across Q|K), K=384 (12 steps), weights streamed
// through LDS in 96-channel chunks (memory-bound on 201 MB of weights).
// ---------------------------------------------------------------------------
__global__ __launch_bounds__(256) void k_proj(
    const float* __restrict__ x, const float* __restrict__ qw,
    const float* __restrict__ qb, const float* __restrict__ kw,
    unsigned short* __restrict__ Qb, unsigned short* __restrict__ Kb) {
  // xs: 16 rows x 384 ch bf16, row stride 392 (16B-aligned rows, conflict-safe)
  __shared__ __attribute__((aligned(16))) short xs[16 * 392];
  // wsb: 128 rows (0..63 = qw row j, 64..127 = kw row j-64) x 96 ch chunk,
  // row stride 104 bf16 = 208 B (16B-aligned)
  __shared__ __attribute__((aligned(16))) short wsb[128 * 104];

  const int pos  = blockIdx.x;
  const int tid  = threadIdx.x;
  const int lane = tid & 63;
  const int w    = tid >> 6;
  const int col  = lane & 15;
  const int quad = lane >> 4;

  // stage x[:, pos, :] -> bf16 LDS (16 rows x 96 float4 = 1536 loads)
#pragma unroll
  for (int r = 0; r < 6; ++r) {
    int li = tid + 256 * r;
    int brow = li / 96, c4 = li % 96;
    float4 v = *(const float4*)&x[(brow * S_ + pos) * D_ + 4 * c4];
    *(bf16x4*)&xs[brow * 392 + 4 * c4] = cvt4(v);
  }

  f32x4 acc0 = {0.f, 0.f, 0.f, 0.f};
  f32x4 acc1 = {0.f, 0.f, 0.f, 0.f};
  const int tt0 = 2 * w, tt1 = 2 * w + 1;   // j-tiles owned by this wave

  for (int chunk = 0; chunk < 4; ++chunk) {
    const int c0 = chunk * 96;
    __syncthreads();   // previous-iteration reads done before restaging
    // stage 128 weight rows x 96 channels (3072 float4 / 256 thr = 12 each)
#pragma unroll
    for (int r = 0; r < 12; ++r) {
      int li = tid + 256 * r;
      int j = li / 24, c4 = li % 24;
      const float* src = (j < 64)
          ? &qw[(pos * 64 + j) * D_ + c0 + 4 * c4]
          : &kw[(pos * 64 + (j - 64)) * D_ + c0 + 4 * c4];
      *(bf16x4*)&wsb[j * 104 + 4 * c4] = cvt4(*(const float4*)src);
    }
    __syncthreads();
#pragma unroll
    for (int ks = 0; ks < 3; ++ks) {
      // A frag: x[m=col][k = c0+ks*32+quad*8 ..+7]
      bf16x8 aF = *(const bf16x8*)&xs[col * 392 + c0 + ks * 32 + quad * 8];
      bf16x8 b0 = *(const bf16x8*)&wsb[(tt0 * 16 + col) * 104 + ks * 32 + quad * 8];
      bf16x8 b1 = *(const bf16x8*)&wsb[(tt1 * 16 + col) * 104 + ks * 32 + quad * 8];
      acc0 = __builtin_amdgcn_mfma_f32_16x16x32_bf16(aF, b0, acc0, 0, 0, 0);
      acc1 = __builtin_amdgcn_mfma_f32_16x16x32_bf16(aF, b1, acc1, 0, 0, 0);
    }
  }

  const float SCALE = 0.051031036307982884f;   // 384^-0.5
#pragma unroll
  for (int a = 0; a < 2; ++a) {
    const f32x4 acc = a ? acc1 : acc0;
    const int tt = a ? tt1 : tt0;
    const int j = tt * 16 + col;           // C/D: col = lane&15
#pragma unroll
    for (int r = 0; r < 4; ++r) {
      const int brow = quad * 4 + r;       // C/D: row = quad*4 + reg
      float v = acc[r];
      if (j < 64) {
        v = SCALE * (v + qb[pos * 64 + j]);
        Qb[(brow * S_ + pos) * QK_ + j] = (unsigned short)f2bf(v);
      } else {
        Kb[(brow * S_ + pos) * QK_ + (j - 64)] = (unsigned short)f2bf(v);
      }
    }
  }
}

// ---------------------------------------------------------------------------
// K2: logits = Q K^T + attn_bias, written fp32 to the attn output region.
// Block = (b, 64 i x 64 j) tile; wave w owns i-sub w, 4 j-subs; K=64 (2 steps)
// ---------------------------------------------------------------------------
__global__ __launch_bounds__(256) void k_logits(
    const unsigned short* __restrict__ Qb, const unsigned short* __restrict__ Kb,
    const float* __restrict__ bias, float* __restrict__ attn) {
  __shared__ __attribute__((aligned(16))) short Qs[64 * 72];
  __shared__ __attribute__((aligned(16))) short Ks[64 * 72];
  const int gid = blockIdx.x;
  const int b = gid >> 8, it = (gid >> 4) & 15, jt = gid & 15;
  const int i0 = it * 64, j0 = jt * 64;
  const int tid = threadIdx.x, lane = tid & 63, w = tid >> 6;
  const int col = lane & 15, quad = lane >> 4;

#pragma unroll
  for (int r = 0; r < 2; ++r) {
    int li = tid + 256 * r;
    int row = li >> 3, q8 = li & 7;
    *(uint4*)&Qs[row * 72 + q8 * 8] =
        *(const uint4*)&Qb[(b * S_ + i0 + row) * QK_ + q8 * 8];
    *(uint4*)&Ks[row * 72 + q8 * 8] =
        *(const uint4*)&Kb[(b * S_ + j0 + row) * QK_ + q8 * 8];
  }
  __syncthreads();

  f32x4 acc[4] = {{0.f,0.f,0.f,0.f},{0.f,0.f,0.f,0.f},
                  {0.f,0.f,0.f,0.f},{0.f,0.f,0.f,0.f}};
#pragma unroll
  for (int ks = 0; ks < 2; ++ks) {
    bf16x8 aF = *(const bf16x8*)&Qs[(w * 16 + col) * 72 + ks * 32 + quad * 8];
#pragma unroll
    for (int s = 0; s < 4; ++s) {
      bf16x8 bF = *(const bf16x8*)&Ks[(s * 16 + col) * 72 + ks * 32 + quad * 8];
      acc[s] = __builtin_amdgcn_mfma_f32_16x16x32_bf16(aF, bF, acc[s], 0, 0, 0);
    }
  }
#pragma unroll
  for (int s = 0; s < 4; ++s) {
    const int j = j0 + s * 16 + col;
#pragma unroll
    for (int r = 0; r < 4; ++r) {
      const int i = i0 + w * 16 + quad * 4 + r;
      attn[(size_t)(b * S_ + i) * S_ + j] = acc[s][r] + bias[i * S_ + j];
    }
  }
}

// ---------------------------------------------------------------------------
// K3: in-place row softmax over 1024 logits. One block per (b,i) row.
// ---------------------------------------------------------------------------
__global__ __launch_bounds__(256) void k_softmax(float* __restrict__ attn) {
  const int tid = threadIdx.x, lane = tid & 63, w = tid >> 6;
  float* p = attn + (size_t)blockIdx.x * S_;
  float4 v = *(const float4*)&p[tid * 4];
  float m = fmaxf(fmaxf(v.x, v.y), fmaxf(v.z, v.w));
#pragma unroll
  for (int off = 32; off > 0; off >>= 1) m = fmaxf(m, __shfl_xor(m, off));
  __shared__ float redm[4], reds[4];
  if (lane == 0) redm[w] = m;
  __syncthreads();
  m = fmaxf(fmaxf(redm[0], redm[1]), fmaxf(redm[2], redm[3]));
  float4 e;
  e.x = __expf(v.x - m); e.y = __expf(v.y - m);
  e.z = __expf(v.z - m); e.w = __expf(v.w - m);
  float s = e.x + e.y + e.z + e.w;
#pragma unroll
  for (int off = 32; off > 0; off >>= 1) s += __shfl_xor(s, off);
  if (lane == 0) reds[w] = s;
  __syncthreads();
  s = reds[0] + reds[1] + reds[2] + reds[3];
  const float inv = 1.0f / s;
  e.x *= inv; e.y *= inv; e.z *= inv; e.w *= inv;
  *(float4*)&p[tid * 4] = e;
}

// ---------------------------------------------------------------------------
// K4: out = P @ X per batch (M=1024, N=384, K=1024). Block = 64 i x 128 c,
// K-loop in steps of 32 j. P converted to bf16 while staging; X staged
// TRANSPOSED (XsT[c][j]) so the B-fragment is a contiguous 16B LDS read.
// ---------------------------------------------------------------------------
__global__ __launch_bounds__(256) void k_out(
    const float* __restrict__ attn, const float* __restrict__ x,
    float* __restrict__ out) {
  __shared__ __attribute__((aligned(16))) short Ps[64 * 40];    // [i][j] bf16
  __shared__ __attribute__((aligned(16))) short XsT[128 * 40];  // [c][j] bf16
  const int gid = blockIdx.x;
  const int b = gid / 48, r48 = gid % 48;
  const int it = r48 / 3, ct = r48 % 3;
  const int i0 = it * 64, c0 = ct * 128;
  const int tid = threadIdx.x, lane = tid & 63, w = tid >> 6;
  const int col = lane & 15, quad = lane >> 4;

  f32x4 acc[8] = {{0.f,0.f,0.f,0.f},{0.f,0.f,0.f,0.f},{0.f,0.f,0.f,0.f},
                  {0.f,0.f,0.f,0.f},{0.f,0.f,0.f,0.f},{0.f,0.f,0.f,0.f},
                  {0.f,0.f,0.f,0.f},{0.f,0.f,0.f,0.f}};

  for (int j0 = 0; j0 < S_; j0 += 32) {
    __syncthreads();
    // stage P tile: 64 i rows x 32 j (bf16)
#pragma unroll
    for (int r = 0; r < 2; ++r) {
      int li = tid + 256 * r;
      int ii = li >> 3, f4 = li & 7;
      float4 v = *(const float4*)&attn[(size_t)(b * S_ + i0 + ii) * S_ + j0 + f4 * 4];
      *(bf16x4*)&Ps[ii * 40 + f4 * 4] = cvt4(v);
    }
    // stage X^T tile: 128 c rows x 32 j (bf16), transposed on LDS write
#pragma unroll
    for (int r = 0; r < 4; ++r) {
      int li = tid + 256 * r;
      int jj = li >> 5, f4 = li & 31;
      float4 v = *(const float4*)&x[(b * S_ + j0 + jj) * D_ + c0 + f4 * 4];
      XsT[(f4 * 4 + 0) * 40 + jj] = f2bf(v.x);
      XsT[(f4 * 4 + 1) * 40 + jj] = f2bf(v.y);
      XsT[(f4 * 4 + 2) * 40 + jj] = f2bf(v.z);
      XsT[(f4 * 4 + 3) * 40 + jj] = f2bf(v.w);
    }
    __syncthreads();
    bf16x8 aF = *(const bf16x8*)&Ps[(w * 16 + col) * 40 + quad * 8];
#pragma unroll
    for (int s = 0; s < 8; ++s) {
      bf16x8 bF = *(const bf16x8*)&XsT[(s * 16 + col) * 40 + quad * 8];
      acc[s] = __builtin_amdgcn_mfma_f32_16x16x32_bf16(aF, bF, acc[s], 0, 0, 0);
    }
  }
#pragma unroll
  for (int s = 0; s < 8; ++s) {
    const int c = c0 + s * 16 + col;
#pragma unroll
    for (int r = 0; r < 4; ++r) {
      const int i = i0 + w * 16 + quad * 4 + r;
      out[(size_t)(b * S_ + i) * D_ + c] = acc[s][r];
    }
  }
}

extern "C" void kernel_launch(void* const* d_in, const int* in_sizes, int n_in,
                              void* d_out, int out_size, void* d_ws, size_t ws_size,
                              hipStream_t stream) {
  const float* x  = (const float*)d_in[0];
  const float* qw = (const float*)d_in[1];
  const float* qb = (const float*)d_in[2];
  const float* kw = (const float*)d_in[3];
  const float* ab = (const float*)d_in[4];

  float* out  = (float*)d_out;
  float* attn = out + (size_t)B_ * S_ * D_;          // outputs concatenated

  unsigned short* Qb = (unsigned short*)d_ws;        // bf16 Q [B][S][64]
  unsigned short* Kb = Qb + (size_t)B_ * S_ * QK_;   // bf16 K [B][S][64]

  k_proj   <<<S_,          256, 0, stream>>>(x, qw, qb, kw, Qb, Kb);
  k_logits <<<B_ * 16 * 16, 256, 0, stream>>>(Qb, Kb, ab, attn);
  k_softmax<<<B_ * S_,     256, 0, stream>>>(attn);
  k_out    <<<B_ * 16 * 3, 256, 0, stream>>>(attn, x, out);
}